// Round 11
// baseline (3590.442 us; speedup 1.0000x reference)
//
#include <hip/hip_runtime.h>
#include <hip/hip_bf16.h>

#define NSTEPS 100
#define DT (1.0f / 100.0f)
#define TSCALE 2.885390081777927f   // 2*log2(e): folded into W1,W2 (and applied to b1,b2 at load)

typedef __attribute__((ext_vector_type(8))) short short8;     // 8 bf16 (32x32x16 A/B frag)
typedef __attribute__((ext_vector_type(16))) float float16;   // 32x32 C/D frag

__device__ __forceinline__ unsigned short f2bf(float f) {
  union { float f; unsigned int u; } v; v.f = f;
  unsigned int u = v.u;
  return (unsigned short)((u + 0x7fffu + ((u >> 16) & 1u)) >> 16);  // RNE
}
__device__ __forceinline__ unsigned int pk2(float a, float b) {
  __hip_bfloat162 h = __float22bfloat162_rn(make_float2(a, b));
  union { __hip_bfloat162 h; unsigned int u; } v; v.h = h;
  return v.u;
}
// tanh with input pre-scaled by 2*log2(e): tanh = 1 - 2/(2^y + 1)
__device__ __forceinline__ float tanh_pre(float y) {
  float e = __builtin_amdgcn_exp2f(y);
  return 1.0f - 2.0f * __builtin_amdgcn_rcpf(e + 1.0f);
}

// Repack W (K x N row-major fp32) into 32x32x16 A-frag-major bf16 (A-frag of W^T):
// element ((s*NT + mt)*64 + l)*8 + j holds W[k = s*16 + 8*(l>>5) + j][n = mt*32 + (l&31)].
// W1/W2 pre-scaled by TSCALE.  (byte-identical to R9's prep — HW-validated)
__global__ void prep_weights(const float* __restrict__ W1,
                             const float* __restrict__ W2,
                             const float* __restrict__ W3,
                             unsigned short* __restrict__ ws) {
  int e = blockIdx.x * 256 + threadIdx.x;  // 98304 total
  const float* src; int N, NT, el, base; float sc;
  if (e < 16384)      { src = W1; N = 256; NT = 8; base = 0;     el = e;         sc = TSCALE; }
  else if (e < 81920) { src = W2; N = 256; NT = 8; base = 16384; el = e - 16384; sc = TSCALE; }
  else                { src = W3; N = 64;  NT = 2; base = 81920; el = e - 81920; sc = 1.0f; }
  int j = el & 7;
  int l = (el >> 3) & 63;
  int rem = el >> 9;
  int mt = rem % NT;
  int s  = rem / NT;
  int k = s * 16 + ((l >> 5) << 3) + j;
  int n = mt * 32 + (l & 31);
  ws[base + el] = f2bf(src[k * N + n] * sc);
}

// 256-thread (4-wave) blocks of 32 batch rows; grid 1024; ~220 regs/wave
// (2 waves/SIMD) and 70.7 KB LDS -> TWO blocks co-resident per CU with
// INDEPENDENT barriers: each SIMD carries one wave from each block, so one
// block's MFMA phases overlap the other's tanh phases (m114 co-scheduling).
// Wave w owns L1/L2 M-tiles {2w,2w+1} (W2=128 regs, W1=32 regs). L3 on
// waves 0-1 (M-tile = w), W3 from LDS. z/zacc in LDS. Biases reloaded per
// iteration from global (L1-hot); `zero*it` defeats LICM so they never
// become 80 hoisted registers.
__global__ __launch_bounds__(256, 2)
void cnf_kernel(const float* __restrict__ z0,
                const float* __restrict__ b1,
                const float* __restrict__ b2,
                const float* __restrict__ b3,
                const unsigned short* __restrict__ wsAll,
                float* __restrict__ out, int zero) {
  extern __shared__ unsigned short smem[];     // 70656 B
  unsigned short* Zbuf = smem;                 //  4096 B (4 tiles  * 512)
  unsigned short* Hbuf = smem + 2048;          // 16384 B (16 tiles * 512)
  unsigned short* LW3  = smem + 10240;         // 32768 B (16 s * 2 mt * 512)
  float*          zws  = (float*)(smem + 26624);  // [2][32][68] f32 = 17408 B

  const int tid  = threadIdx.x;
  const int w    = tid >> 6;        // 4 waves
  const int lane = tid & 63;
  const int i31  = lane & 31;
  const int h4   = (lane >> 5) * 4; // 0 or 4
  const int grow = blockIdx.x * 32;

  const unsigned short* wsW1 = wsAll;
  const unsigned short* wsW2 = wsAll + 16384;
  const unsigned short* wsW3 = wsAll + 81920;

  // ---- anti-phase-lock stagger: odd blocks burn ~1.6K cyc (thread 0 only) ----
  if ((blockIdx.x & 1) && tid == 0) {
    float v = z0[0];
#pragma unroll 1
    for (int i = 0; i < 400; ++i) v = __builtin_fmaf(v, 1.000001f, 1e-7f);
    atomicAdd(&zws[0], v);   // overwritten by z-init after the barrier below
  }

  // ---- W3 -> LDS (once): 2048 uint4 over 256 threads ----
  {
    const uint4* s3 = (const uint4*)wsW3;
    uint4* d3 = (uint4*)LW3;
#pragma unroll
    for (int i = 0; i < 8; ++i) d3[tid + 256 * i] = s3[tid + 256 * i];
  }

  // ---- register-resident W1 (32) + W2 (128) A-frags, M-tiles {2w, 2w+1} ----
  short8 w1f[4][2], w2f[16][2];
#pragma unroll
  for (int s = 0; s < 4; ++s)
#pragma unroll
    for (int t = 0; t < 2; ++t)
      w1f[s][t] = *(const short8*)&wsW1[((s * 8 + 2 * w + t) * 64 + lane) * 8];
#pragma unroll
  for (int s = 0; s < 16; ++s)
#pragma unroll
    for (int t = 0; t < 2; ++t)
      w2f[s][t] = *(const short8*)&wsW2[((s * 8 + 2 * w + t) * 64 + lane) * 8];

  __syncthreads();   // stagger + LW3 ordering vs z-init below

  // ---- z init (waves 0,1): zws + Zbuf ----
  if (w < 2) {
#pragma unroll
    for (int g = 0; g < 4; ++g) {
      float4 v = *(const float4*)&z0[(grow + i31) * 64 + w * 32 + 8 * g + h4];
      *(float4*)&zws[i31 * 68 + w * 32 + 8 * g + h4] = v;
      uint2 p; p.x = pk2(v.x, v.y); p.y = pk2(v.z, v.w);
      *(uint2*)&Zbuf[((2 * w + (g >> 1)) * 64 + i31 + 32 * (g & 1)) * 8 + h4] = p;
    }
  }

  const float DT6 = DT / 6.0f, DT3 = DT / 3.0f, DTH = 0.5f * DT;
  const int rb = lane * 8;              // activation frag read base; tile adds *512
  float* zacc = zws + 2176;             // second [32][68] array

#pragma unroll 1
  for (int it = 0; it < NSTEPS * 4; ++it) {
    const int st = it & 3;
    const int zo = zero * it;           // 0 at runtime; defeats LICM of bias loads
    __syncthreads();  // B1: Zbuf stage visible; prev L3 Hbuf reads done

    // ---- Layer 1: K=64, acc init = TSCALE*b1 (fresh load each it) ----
    float16 acc[2];
#pragma unroll
    for (int t = 0; t < 2; ++t)
#pragma unroll
      for (int g = 0; g < 4; ++g) {
        float4 c = *(const float4*)&b1[(2 * w + t) * 32 + 8 * g + h4 + zo];
        acc[t][4 * g + 0] = c.x * TSCALE; acc[t][4 * g + 1] = c.y * TSCALE;
        acc[t][4 * g + 2] = c.z * TSCALE; acc[t][4 * g + 3] = c.w * TSCALE;
      }
#pragma unroll
    for (int s = 0; s < 4; ++s) {
      short8 bz = *(const short8*)&Zbuf[rb + s * 512];
      acc[0] = __builtin_amdgcn_mfma_f32_32x32x16_bf16(w1f[s][0], bz, acc[0], 0, 0, 0);
      acc[1] = __builtin_amdgcn_mfma_f32_32x32x16_bf16(w1f[s][1], bz, acc[1], 0, 0, 0);
    }
    // E1 -> Hbuf (tile s16 = 2*mt + (g>>1))
#pragma unroll
    for (int t = 0; t < 2; ++t)
#pragma unroll
      for (int g = 0; g < 4; ++g) {
        uint2 p;
        p.x = pk2(tanh_pre(acc[t][4 * g + 0]), tanh_pre(acc[t][4 * g + 1]));
        p.y = pk2(tanh_pre(acc[t][4 * g + 2]), tanh_pre(acc[t][4 * g + 3]));
        *(uint2*)&Hbuf[((2 * (2 * w + t) + (g >> 1)) * 64 + i31 + 32 * (g & 1)) * 8 + h4] = p;
      }
    __syncthreads();  // B2: H1 visible

    // ---- Layer 2: K=256, acc init = TSCALE*b2 ----
    float16 a2[2];
#pragma unroll
    for (int t = 0; t < 2; ++t)
#pragma unroll
      for (int g = 0; g < 4; ++g) {
        float4 c = *(const float4*)&b2[(2 * w + t) * 32 + 8 * g + h4 + zo];
        a2[t][4 * g + 0] = c.x * TSCALE; a2[t][4 * g + 1] = c.y * TSCALE;
        a2[t][4 * g + 2] = c.z * TSCALE; a2[t][4 * g + 3] = c.w * TSCALE;
      }
#pragma unroll
    for (int s = 0; s < 16; ++s) {
      short8 bh = *(const short8*)&Hbuf[rb + s * 512];
      a2[0] = __builtin_amdgcn_mfma_f32_32x32x16_bf16(w2f[s][0], bh, a2[0], 0, 0, 0);
      a2[1] = __builtin_amdgcn_mfma_f32_32x32x16_bf16(w2f[s][1], bh, a2[1], 0, 0, 0);
    }
    __syncthreads();  // B3: all H1 reads done -> Hbuf may be overwritten

    // E2 -> Hbuf (H2, same layout)
#pragma unroll
    for (int t = 0; t < 2; ++t)
#pragma unroll
      for (int g = 0; g < 4; ++g) {
        uint2 p;
        p.x = pk2(tanh_pre(a2[t][4 * g + 0]), tanh_pre(a2[t][4 * g + 1]));
        p.y = pk2(tanh_pre(a2[t][4 * g + 2]), tanh_pre(a2[t][4 * g + 3]));
        *(uint2*)&Hbuf[((2 * (2 * w + t) + (g >> 1)) * 64 + i31 + 32 * (g & 1)) * 8 + h4] = p;
      }
    __syncthreads();  // B4: H2 visible

    // ---- Layer 3 + RK4 (waves 0,1; mt = w) ----
    if (w < 2) {
      float16 a3;
#pragma unroll
      for (int g = 0; g < 4; ++g) {
        float4 c = *(const float4*)&b3[w * 32 + 8 * g + h4 + zo];
        a3[4 * g + 0] = c.x; a3[4 * g + 1] = c.y;
        a3[4 * g + 2] = c.z; a3[4 * g + 3] = c.w;
      }
#pragma unroll
      for (int s = 0; s < 16; ++s) {
        short8 wf = *(const short8*)&LW3[rb + (s * 2 + w) * 512];
        short8 bh = *(const short8*)&Hbuf[rb + s * 512];
        a3 = __builtin_amdgcn_mfma_f32_32x32x16_bf16(wf, bh, a3, 0, 0, 0);
      }
      const float wsum  = (st == 0 || st == 3) ? DT6 : DT3;
      const float cst   = (st == 2) ? DT : DTH;
      const bool  last  = (st == 3);
      const bool  first = (st == 0);
#pragma unroll
      for (int g = 0; g < 4; ++g) {
        const int zi = i31 * 68 + w * 32 + 8 * g + h4;
        float4 zv = *(const float4*)&zws[zi];
        float4 av = first ? zv : *(const float4*)&zacc[zi];
        float k0 = a3[4 * g + 0], k1 = a3[4 * g + 1], k2 = a3[4 * g + 2], k3 = a3[4 * g + 3];
        float4 za;
        za.x = (first ? zv.x : av.x) + wsum * k0;
        za.y = (first ? zv.y : av.y) + wsum * k1;
        za.z = (first ? zv.z : av.z) + wsum * k2;
        za.w = (first ? zv.w : av.w) + wsum * k3;
        *(float4*)&zacc[zi] = za;
        float4 stg;
        if (last) { *(float4*)&zws[zi] = za; stg = za; }
        else {
          stg.x = zv.x + cst * k0; stg.y = zv.y + cst * k1;
          stg.z = zv.z + cst * k2; stg.w = zv.w + cst * k3;
        }
        uint2 p; p.x = pk2(stg.x, stg.y); p.y = pk2(stg.z, stg.w);
        *(uint2*)&Zbuf[((2 * w + (g >> 1)) * 64 + i31 + 32 * (g & 1)) * 8 + h4] = p;
      }
    }
  }

  // ---- final store (waves 0,1) ----
  if (w < 2) {
#pragma unroll
    for (int g = 0; g < 4; ++g) {
      float4 v = *(const float4*)&zws[i31 * 68 + w * 32 + 8 * g + h4];
      *(float4*)&out[(grow + i31) * 64 + w * 32 + 8 * g + h4] = v;
    }
  }
}

extern "C" void kernel_launch(void* const* d_in, const int* in_sizes, int n_in,
                              void* d_out, int out_size, void* d_ws, size_t ws_size,
                              hipStream_t stream) {
  const float* z0 = (const float*)d_in[0];
  const float* W1 = (const float*)d_in[1];
  const float* b1 = (const float*)d_in[2];
  const float* W2 = (const float*)d_in[3];
  const float* b2 = (const float*)d_in[4];
  const float* W3 = (const float*)d_in[5];
  const float* b3 = (const float*)d_in[6];
  unsigned short* ws = (unsigned short*)d_ws;  // 98304 bf16 = 196608 B

  prep_weights<<<384, 256, 0, stream>>>(W1, W2, W3, ws);
  (void)hipFuncSetAttribute((const void*)cnf_kernel,
                            hipFuncAttributeMaxDynamicSharedMemorySize, 70656);
  cnf_kernel<<<1024, 256, 70656, stream>>>(z0, b1, b2, b3, ws, (float*)d_out, 0);
}

// Round 12
// 3232.698 us; speedup vs baseline: 1.1107x; 1.1107x over previous
//
#include <hip/hip_runtime.h>
#include <hip/hip_bf16.h>

#define NSTEPS 100
#define DT (1.0f / 100.0f)
#define TSCALE 2.885390081777927f   // 2*log2(e): folded into W1,W2 (b1,b2 scaled at load)

typedef __attribute__((ext_vector_type(8))) short short8;   // 8 bf16 (16x16x32 A/B frag)
typedef __attribute__((ext_vector_type(4))) float floatx4;  // 16x16 C/D frag

__device__ __forceinline__ unsigned short f2bf(float f) {
  union { float f; unsigned int u; } v; v.f = f;
  unsigned int u = v.u;
  return (unsigned short)((u + 0x7fffu + ((u >> 16) & 1u)) >> 16);  // RNE
}
__device__ __forceinline__ unsigned int pk2(float a, float b) {
  __hip_bfloat162 h = __float22bfloat162_rn(make_float2(a, b));
  union { __hip_bfloat162 h; unsigned int u; } v; v.h = h;
  return v.u;
}
// tanh with input pre-scaled by 2*log2(e): tanh = 1 - 2/(2^y + 1)
__device__ __forceinline__ float tanh_pre(float y) {
  float e = __builtin_amdgcn_exp2f(y);
  return 1.0f - 2.0f * __builtin_amdgcn_rcpf(e + 1.0f);
}

// Repack W (K x N row-major fp32) into 16x16x32 frag-major bf16 (A-frag of W^T):
// element ((s*ntiles + t)*64 + l)*8 + j holds W[k=s*32+(l>>4)*8+j][n=t*16+(l&15)].
// W1/W2 pre-scaled by TSCALE.  (R5-era prep — HW-validated R5-R8)
__global__ void prep_weights(const float* __restrict__ W1,
                             const float* __restrict__ W2,
                             const float* __restrict__ W3,
                             unsigned short* __restrict__ ws) {
  int e = blockIdx.x * 256 + threadIdx.x;  // 98304 total
  const float* src; int N, ntile, el, base; float sc;
  if (e < 16384)      { src = W1; N = 256; ntile = 16; base = 0;     el = e;         sc = TSCALE; }
  else if (e < 81920) { src = W2; N = 256; ntile = 16; base = 16384; el = e - 16384; sc = TSCALE; }
  else                { src = W3; N = 64;  ntile = 4;  base = 81920; el = e - 81920; sc = 1.0f; }
  int j = el & 7;
  int l = (el >> 3) & 63;
  int rem = el >> 9;
  int t = rem % ntile;
  int s = rem / ntile;
  int k = s * 32 + ((l >> 4) << 3) + j;
  int n = t * 16 + (l & 15);
  ws[base + el] = f2bf(src[k * N + n] * sc);
}

// 1024-thread block (16 waves, 4 waves/SIMD — double the session's occupancy),
// one block per CU, grid 512 (2 rounds). Wave w owns M-tile w for L1/L2
// (W1=8, W2=32 VGPR) and L3 output tile (mt=w&3, ntw=w>>2). W3 + z/zacc in
// LDS; biases reloaded per-it from global (zero-trick defeats LICM; kept
// VGPR at 120 in R10). All LDS layouts = R5-validated frag-major 16x16x32.
__global__ __launch_bounds__(1024, 4)
void cnf_kernel(const float* __restrict__ z0,
                const float* __restrict__ b1,
                const float* __restrict__ b2,
                const float* __restrict__ b3,
                const unsigned short* __restrict__ wsAll,
                float* __restrict__ out, int zero) {
  extern __shared__ unsigned short smem[];        // 108544 B
  unsigned short* Zbuf = smem;                    //  8192 B (4 nt * 2 s * 512)
  unsigned short* Hbuf = smem + 4096;             // 32768 B (4 nt * 8 s * 512)
  unsigned short* LW3  = smem + 20480;            // 32768 B (8 s * 4 mt * 512)
  float*          zws  = (float*)(smem + 36864);  // 2 x [64][68] f32 = 34816 B

  const int tid  = threadIdx.x;
  const int w    = tid >> 6;        // 16 waves
  const int lane = tid & 63;
  const int i15  = lane & 15;
  const int q    = lane >> 4;
  const int grow = blockIdx.x * 64;
  const int mt   = w & 3;           // L3 M-tile
  const int ntw  = w >> 2;          // L3 N-tile

  const unsigned short* wsW1 = wsAll;
  const unsigned short* wsW2 = wsAll + 16384;
  const unsigned short* wsW3 = wsAll + 81920;

  // ---- W3 -> LDS (once): 2048 uint4 over 1024 threads ----
  {
    const uint4* s3 = (const uint4*)wsW3;
    uint4* d3 = (uint4*)LW3;
    d3[tid] = s3[tid];
    d3[tid + 1024] = s3[tid + 1024];
  }

  // ---- register-resident W1 (8 VGPR) + W2 (32 VGPR) A-frags, M-tile = w ----
  short8 w1f[2], w2f[8];
#pragma unroll
  for (int s = 0; s < 2; ++s)
    w1f[s] = *(const short8*)&wsW1[((s * 16 + w) * 64 + lane) * 8];
#pragma unroll
  for (int s = 0; s < 8; ++s)
    w2f[s] = *(const short8*)&wsW2[((s * 16 + w) * 64 + lane) * 8];

  // ---- frag-layout index bases ----
  const int rb  = lane * 8;                 // B-frag read base; tile adds *512
  const int j0  = 4 * (q & 1);
  // E-write (M-tile w): s=w>>1, d=2*(w&1)+(q>>1)
  const int hwE = (((w >> 1)) * 64 + i15 + 16 * (2 * (w & 1) + (q >> 1))) * 8 + j0;  // +nt*4096
  // Z-stage write (M-tile mt): s=mt>>1, d=2*(mt&1)+(q>>1); Zbuf tile = ntw*2+s
  const int zwS = ((ntw * 2 + (mt >> 1)) * 64 + i15 + 16 * (2 * (mt & 1) + (q >> 1))) * 8 + j0;
  const int w3b = mt * 512 + lane * 8;      // + s*2048
  const int zi  = (ntw * 16 + i15) * 68 + mt * 16 + 4 * q;   // zws float4 index
  float* zacc = zws + 64 * 68;

  // ---- z init: every wave inits its own (mt,ntw) tile ----
  {
    float4 v = *(const float4*)&z0[(grow + ntw * 16 + i15) * 64 + mt * 16 + 4 * q];
    *(float4*)&zws[zi] = v;
    zacc[zi] = 0.f;   // contents set properly at st==0; touch to init
    uint2 p; p.x = pk2(v.x, v.y); p.y = pk2(v.z, v.w);
    *(uint2*)&Zbuf[zwS] = p;
  }

  const float DT6 = DT / 6.0f, DT3 = DT / 3.0f, DTH = 0.5f * DT;

#pragma unroll 1
  for (int it = 0; it < NSTEPS * 4; ++it) {
    const int st = it & 3;
    const int zo = zero * it;     // 0 at runtime; defeats LICM of bias loads
    __syncthreads();  // B1: Zbuf stage + (init: LW3/Zbuf) visible; prev P3 Hbuf reads done

    // ---- Layer 1: K=64, acc init = TSCALE*b1 (fresh load) ----
    floatx4 acc[4];
    {
      float4 c = *(const float4*)&b1[w * 16 + 4 * q + zo];
      floatx4 ci = floatx4{c.x * TSCALE, c.y * TSCALE, c.z * TSCALE, c.w * TSCALE};
#pragma unroll
      for (int nt = 0; nt < 4; ++nt) acc[nt] = ci;
    }
#pragma unroll
    for (int s = 0; s < 2; ++s)
#pragma unroll
      for (int nt = 0; nt < 4; ++nt) {
        short8 bz = *(const short8*)&Zbuf[rb + (nt * 2 + s) * 512];
        acc[nt] = __builtin_amdgcn_mfma_f32_16x16x32_bf16(w1f[s], bz, acc[nt], 0, 0, 0);
      }
    // E1 -> Hbuf
#pragma unroll
    for (int nt = 0; nt < 4; ++nt) {
      uint2 p;
      p.x = pk2(tanh_pre(acc[nt][0]), tanh_pre(acc[nt][1]));
      p.y = pk2(tanh_pre(acc[nt][2]), tanh_pre(acc[nt][3]));
      *(uint2*)&Hbuf[hwE + nt * 4096] = p;
    }
    __syncthreads();  // B2: H1 visible

    // ---- Layer 2: K=256, acc init = TSCALE*b2 ----
    floatx4 a2[4];
    {
      float4 c = *(const float4*)&b2[w * 16 + 4 * q + zo];
      floatx4 ci = floatx4{c.x * TSCALE, c.y * TSCALE, c.z * TSCALE, c.w * TSCALE};
#pragma unroll
      for (int nt = 0; nt < 4; ++nt) a2[nt] = ci;
    }
#pragma unroll
    for (int s = 0; s < 8; ++s)
#pragma unroll
      for (int nt = 0; nt < 4; ++nt) {
        short8 bh = *(const short8*)&Hbuf[rb + (nt * 8 + s) * 512];
        a2[nt] = __builtin_amdgcn_mfma_f32_16x16x32_bf16(w2f[s], bh, a2[nt], 0, 0, 0);
      }
    __syncthreads();  // B3: all H1 reads done -> Hbuf may be overwritten

    // E2 -> Hbuf
#pragma unroll
    for (int nt = 0; nt < 4; ++nt) {
      uint2 p;
      p.x = pk2(tanh_pre(a2[nt][0]), tanh_pre(a2[nt][1]));
      p.y = pk2(tanh_pre(a2[nt][2]), tanh_pre(a2[nt][3]));
      *(uint2*)&Hbuf[hwE + nt * 4096] = p;
    }
    __syncthreads();  // B4: H2 visible

    // ---- Layer 3 + RK4: every wave does output tile (mt, ntw) ----
    {
      floatx4 a3;
      {
        float4 c = *(const float4*)&b3[mt * 16 + 4 * q + zo];
        a3 = floatx4{c.x, c.y, c.z, c.w};
      }
#pragma unroll
      for (int s = 0; s < 8; ++s) {
        short8 wf = *(const short8*)&LW3[w3b + s * 2048];
        short8 bh = *(const short8*)&Hbuf[rb + (ntw * 8 + s) * 512];
        a3 = __builtin_amdgcn_mfma_f32_16x16x32_bf16(wf, bh, a3, 0, 0, 0);
      }
      const float wsum  = (st == 0 || st == 3) ? DT6 : DT3;
      const float cst   = (st == 2) ? DT : DTH;
      const bool  last  = (st == 3);
      const bool  first = (st == 0);
      float4 zv = *(const float4*)&zws[zi];
      float4 av; 
      if (first) { av = zv; } else { av = *(const float4*)&zacc[zi]; }
      float4 za, stg;
      za.x = av.x + wsum * a3[0]; za.y = av.y + wsum * a3[1];
      za.z = av.z + wsum * a3[2]; za.w = av.w + wsum * a3[3];
      *(float4*)&zacc[zi] = za;
      if (last) {
        *(float4*)&zws[zi] = za;
        stg = za;
      } else {
        stg.x = zv.x + cst * a3[0]; stg.y = zv.y + cst * a3[1];
        stg.z = zv.z + cst * a3[2]; stg.w = zv.w + cst * a3[3];
      }
      uint2 p; p.x = pk2(stg.x, stg.y); p.y = pk2(stg.z, stg.w);
      *(uint2*)&Zbuf[zwS] = p;
    }
  }

  // ---- final store: each wave stores its tile ----
  {
    float4 v = *(const float4*)&zws[zi];
    *(float4*)&out[(grow + ntw * 16 + i15) * 64 + mt * 16 + 4 * q] = v;
  }
}

extern "C" void kernel_launch(void* const* d_in, const int* in_sizes, int n_in,
                              void* d_out, int out_size, void* d_ws, size_t ws_size,
                              hipStream_t stream) {
  const float* z0 = (const float*)d_in[0];
  const float* W1 = (const float*)d_in[1];
  const float* b1 = (const float*)d_in[2];
  const float* W2 = (const float*)d_in[3];
  const float* b2 = (const float*)d_in[4];
  const float* W3 = (const float*)d_in[5];
  const float* b3 = (const float*)d_in[6];
  unsigned short* ws = (unsigned short*)d_ws;  // 98304 bf16 = 196608 B

  prep_weights<<<384, 256, 0, stream>>>(W1, W2, W3, ws);
  (void)hipFuncSetAttribute((const void*)cnf_kernel,
                            hipFuncAttributeMaxDynamicSharedMemorySize, 108544);
  cnf_kernel<<<512, 1024, 108544, stream>>>(z0, b1, b2, b3, ws, (float*)d_out, 0);
}

// Round 13
// 2848.984 us; speedup vs baseline: 1.2603x; 1.1347x over previous
//
#include <hip/hip_runtime.h>
#include <hip/hip_bf16.h>

#define NSTEPS 100
#define DT (1.0f / 100.0f)
#define TSCALE 2.885390081777927f   // 2*log2(e): folded into W1,W2 (b1,b2 scaled at load)

typedef __attribute__((ext_vector_type(8))) short short8;   // 8 bf16 (16x16x32 A/B frag)
typedef __attribute__((ext_vector_type(4))) float floatx4;  // 16x16 C/D frag

__device__ __forceinline__ unsigned short f2bf(float f) {
  union { float f; unsigned int u; } v; v.f = f;
  unsigned int u = v.u;
  return (unsigned short)((u + 0x7fffu + ((u >> 16) & 1u)) >> 16);  // RNE
}
__device__ __forceinline__ unsigned int pk2(float a, float b) {
  __hip_bfloat162 h = __float22bfloat162_rn(make_float2(a, b));
  union { __hip_bfloat162 h; unsigned int u; } v; v.h = h;
  return v.u;
}
// tanh with input pre-scaled by 2*log2(e): tanh = 1 - 2/(2^y + 1)
__device__ __forceinline__ float tanh_pre(float y) {
  float e = __builtin_amdgcn_exp2f(y);
  return 1.0f - 2.0f * __builtin_amdgcn_rcpf(e + 1.0f);
}

// Repack W (K x N row-major fp32) into 16x16x32 frag-major bf16 (A-frag of W^T):
// element ((s*ntiles + t)*64 + l)*8 + j holds W[k=s*32+(l>>4)*8+j][n=t*16+(l&15)].
// W1/W2 pre-scaled by TSCALE.  (R5-era prep — HW-validated R5-R8, R11)
__global__ void prep_weights(const float* __restrict__ W1,
                             const float* __restrict__ W2,
                             const float* __restrict__ W3,
                             unsigned short* __restrict__ ws) {
  int e = blockIdx.x * 256 + threadIdx.x;  // 98304 total
  const float* src; int N, ntile, el, base; float sc;
  if (e < 16384)      { src = W1; N = 256; ntile = 16; base = 0;     el = e;         sc = TSCALE; }
  else if (e < 81920) { src = W2; N = 256; ntile = 16; base = 16384; el = e - 16384; sc = TSCALE; }
  else                { src = W3; N = 64;  ntile = 4;  base = 81920; el = e - 81920; sc = 1.0f; }
  int j = el & 7;
  int l = (el >> 3) & 63;
  int rem = el >> 9;
  int t = rem % ntile;
  int s = rem / ntile;
  int k = s * 32 + ((l >> 4) << 3) + j;
  int n = t * 16 + (l & 15);
  ws[base + el] = f2bf(src[k * N + n] * sc);
}

// R11 occupancy structure, un-handicapped:
// 1024-thread block (16 waves, 4 waves/SIMD), 1 block/CU, grid 512.
// Wave w: L1/L2 M-tile w (W1=8, W2=32 VGPR register A-frags); L3 output
// tile (mt=w&3, ntw=w>>2) with W3 from LDS. Biases in registers (12 f32),
// z/zacc in registers (32 f32) — NO in-loop VMEM, no z-LDS traffic (the
// two handicaps that contaminated R11). Separate H1/H2 LDS buffers remove
// one barrier: 3 __syncthreads per stage.
__global__ __launch_bounds__(1024, 4)
void cnf_kernel(const float* __restrict__ z0,
                const float* __restrict__ b1,
                const float* __restrict__ b2,
                const float* __restrict__ b3,
                const unsigned short* __restrict__ wsAll,
                float* __restrict__ out) {
  extern __shared__ unsigned short smem[];        // 106496 B
  unsigned short* Zbuf  = smem;                   //  8192 B (4 nt * 2 s * 512)
  unsigned short* Hbuf1 = smem + 4096;            // 32768 B (4 nt * 8 s * 512)
  unsigned short* Hbuf2 = smem + 20480;           // 32768 B
  unsigned short* LW3   = smem + 36864;           // 32768 B (8 s * 4 mt * 512)

  const int tid  = threadIdx.x;
  const int w    = tid >> 6;        // 16 waves
  const int lane = tid & 63;
  const int i15  = lane & 15;
  const int q    = lane >> 4;
  const int grow = blockIdx.x * 64;
  const int mt   = w & 3;           // L3 M-tile
  const int ntw  = w >> 2;          // L3 N-tile

  const unsigned short* wsW1 = wsAll;
  const unsigned short* wsW2 = wsAll + 16384;
  const unsigned short* wsW3 = wsAll + 81920;

  // ---- W3 -> LDS (once): 2048 uint4 over 1024 threads ----
  {
    const uint4* s3 = (const uint4*)wsW3;
    uint4* d3 = (uint4*)LW3;
    d3[tid] = s3[tid];
    d3[tid + 1024] = s3[tid + 1024];
  }

  // ---- register-resident W1 (8 VGPR) + W2 (32 VGPR) A-frags, M-tile = w ----
  short8 w1f[2], w2f[8];
#pragma unroll
  for (int s = 0; s < 2; ++s)
    w1f[s] = *(const short8*)&wsW1[((s * 16 + w) * 64 + lane) * 8];
#pragma unroll
  for (int s = 0; s < 8; ++s)
    w2f[s] = *(const short8*)&wsW2[((s * 16 + w) * 64 + lane) * 8];

  // ---- biases in registers (12 f32), b1/b2 pre-scaled ----
  float b1a[4], b2a[4], b3a[4];
  {
    float4 c1 = *(const float4*)&b1[w * 16 + 4 * q];
    float4 c2 = *(const float4*)&b2[w * 16 + 4 * q];
    float4 c3 = *(const float4*)&b3[mt * 16 + 4 * q];
    b1a[0] = c1.x * TSCALE; b1a[1] = c1.y * TSCALE; b1a[2] = c1.z * TSCALE; b1a[3] = c1.w * TSCALE;
    b2a[0] = c2.x * TSCALE; b2a[1] = c2.y * TSCALE; b2a[2] = c2.z * TSCALE; b2a[3] = c2.w * TSCALE;
    b3a[0] = c3.x; b3a[1] = c3.y; b3a[2] = c3.z; b3a[3] = c3.w;
  }

  // ---- frag-layout index bases ----
  const int rb  = lane * 8;                 // B-frag read base; tile adds *512
  const int j0  = 4 * (q & 1);
  // E-write (M-tile w): s=w>>1, d=2*(w&1)+(q>>1)
  const int hwE = (((w >> 1)) * 64 + i15 + 16 * (2 * (w & 1) + (q >> 1))) * 8 + j0;  // +nt*4096
  // Z-stage write (M-tile mt): s=mt>>1, d=2*(mt&1)+(q>>1); Zbuf tile = ntw*2+s
  const int zwS = ((ntw * 2 + (mt >> 1)) * 64 + i15 + 16 * (2 * (mt & 1) + (q >> 1))) * 8 + j0;
  const int w3b = mt * 512 + lane * 8;      // + s*2048

  // ---- RK4 state in registers: wave's own (mt,ntw) tile ----
  float z[4], zacc[4];
  {
    float4 v = *(const float4*)&z0[(grow + ntw * 16 + i15) * 64 + mt * 16 + 4 * q];
    z[0] = v.x; z[1] = v.y; z[2] = v.z; z[3] = v.w;
    zacc[0] = zacc[1] = zacc[2] = zacc[3] = 0.f;
    uint2 p; p.x = pk2(v.x, v.y); p.y = pk2(v.z, v.w);
    *(uint2*)&Zbuf[zwS] = p;
  }

  const float DT6 = DT / 6.0f, DT3 = DT / 3.0f, DTH = 0.5f * DT;

#pragma unroll 1
  for (int it = 0; it < NSTEPS * 4; ++it) {
    const int st = it & 3;
    __syncthreads();  // B1: Zbuf stage visible (first iter: + LW3); prev P3 Hbuf2 reads done

    // ---- Layer 1: K=64, acc init = b1 (regs) ----
    floatx4 acc[4];
#pragma unroll
    for (int nt = 0; nt < 4; ++nt) acc[nt] = floatx4{b1a[0], b1a[1], b1a[2], b1a[3]};
#pragma unroll
    for (int s = 0; s < 2; ++s)
#pragma unroll
      for (int nt = 0; nt < 4; ++nt) {
        short8 bz = *(const short8*)&Zbuf[rb + (nt * 2 + s) * 512];
        acc[nt] = __builtin_amdgcn_mfma_f32_16x16x32_bf16(w1f[s], bz, acc[nt], 0, 0, 0);
      }
    // E1 -> Hbuf1
#pragma unroll
    for (int nt = 0; nt < 4; ++nt) {
      uint2 p;
      p.x = pk2(tanh_pre(acc[nt][0]), tanh_pre(acc[nt][1]));
      p.y = pk2(tanh_pre(acc[nt][2]), tanh_pre(acc[nt][3]));
      *(uint2*)&Hbuf1[hwE + nt * 4096] = p;
    }
    __syncthreads();  // B2: H1 visible

    // ---- Layer 2: K=256, acc init = b2 ----
    floatx4 a2[4];
#pragma unroll
    for (int nt = 0; nt < 4; ++nt) a2[nt] = floatx4{b2a[0], b2a[1], b2a[2], b2a[3]};
#pragma unroll
    for (int s = 0; s < 8; ++s)
#pragma unroll
      for (int nt = 0; nt < 4; ++nt) {
        short8 bh = *(const short8*)&Hbuf1[rb + (nt * 8 + s) * 512];
        a2[nt] = __builtin_amdgcn_mfma_f32_16x16x32_bf16(w2f[s], bh, a2[nt], 0, 0, 0);
      }
    // E2 -> Hbuf2 (separate buffer: no barrier needed before writing)
#pragma unroll
    for (int nt = 0; nt < 4; ++nt) {
      uint2 p;
      p.x = pk2(tanh_pre(a2[nt][0]), tanh_pre(a2[nt][1]));
      p.y = pk2(tanh_pre(a2[nt][2]), tanh_pre(a2[nt][3]));
      *(uint2*)&Hbuf2[hwE + nt * 4096] = p;
    }
    __syncthreads();  // B3: H2 visible

    // ---- Layer 3 + RK4: wave's tile (mt, ntw), W3 from LDS ----
    {
      floatx4 a3 = floatx4{b3a[0], b3a[1], b3a[2], b3a[3]};
#pragma unroll
      for (int s = 0; s < 8; ++s) {
        short8 wf = *(const short8*)&LW3[w3b + s * 2048];
        short8 bh = *(const short8*)&Hbuf2[rb + (ntw * 8 + s) * 512];
        a3 = __builtin_amdgcn_mfma_f32_16x16x32_bf16(wf, bh, a3, 0, 0, 0);
      }
      const float wsum  = (st == 0 || st == 3) ? DT6 : DT3;
      const float cst   = (st == 2) ? DT : DTH;
      const bool  last  = (st == 3);
      const bool  first = (st == 0);
      float stg[4];
#pragma unroll
      for (int r = 0; r < 4; ++r) {
        float k = a3[r];
        float za = first ? z[r] : zacc[r];
        za += wsum * k;
        zacc[r] = za;
        if (last) { z[r] = za; stg[r] = za; }
        else      { stg[r] = z[r] + cst * k; }
      }
      uint2 p; p.x = pk2(stg[0], stg[1]); p.y = pk2(stg[2], stg[3]);
      *(uint2*)&Zbuf[zwS] = p;
    }
  }

  // ---- final store: each wave stores its tile ----
  {
    float4 v; v.x = z[0]; v.y = z[1]; v.z = z[2]; v.w = z[3];
    *(float4*)&out[(grow + ntw * 16 + i15) * 64 + mt * 16 + 4 * q] = v;
  }
}

extern "C" void kernel_launch(void* const* d_in, const int* in_sizes, int n_in,
                              void* d_out, int out_size, void* d_ws, size_t ws_size,
                              hipStream_t stream) {
  const float* z0 = (const float*)d_in[0];
  const float* W1 = (const float*)d_in[1];
  const float* b1 = (const float*)d_in[2];
  const float* W2 = (const float*)d_in[3];
  const float* b2 = (const float*)d_in[4];
  const float* W3 = (const float*)d_in[5];
  const float* b3 = (const float*)d_in[6];
  unsigned short* ws = (unsigned short*)d_ws;  // 98304 bf16 = 196608 B

  prep_weights<<<384, 256, 0, stream>>>(W1, W2, W3, ws);
  (void)hipFuncSetAttribute((const void*)cnf_kernel,
                            hipFuncAttributeMaxDynamicSharedMemorySize, 106496);
  cnf_kernel<<<512, 1024, 106496, stream>>>(z0, b1, b2, b3, ws, (float*)d_out);
}